// Round 1
// baseline (5641.792 us; speedup 1.0000x reference)
//
#include <hip/hip_runtime.h>

#define N_USERS 100000
#define N_ITEMS 50000
#define NTOT    150000
#define NNZ     10000000
#define D       64
#define NHOPS   3
#define EDGE_SCALE 2.0f
#define MESS_SCALE (1.0f/0.9f)

// ---------------------------------------------------------------------------
// Mask-dtype self-calibration: reference masks are jnp bool; harness may ship
// them as 1-byte bools or widened 4-byte ints/floats. Scan first 1024 words of
// edge_mask (p=0.5 random): if any word is outside {0,1,0x3f800000}, the
// buffer must be packed 1-byte bools. Writes flag (1 = byte masks) to ws.
// ---------------------------------------------------------------------------
__global__ void detect_mask_kernel(const unsigned int* __restrict__ em,
                                   int* __restrict__ flag) {
    __shared__ int s;
    if (threadIdx.x == 0) s = 0;
    __syncthreads();
    for (int i = threadIdx.x; i < 1024; i += blockDim.x) {
        unsigned int w = em[i];
        if (w != 0u && w != 1u && w != 0x3f800000u) s = 1;  // benign race
    }
    __syncthreads();
    if (threadIdx.x == 0) *flag = s;
}

// out[n, 0, :] = concat(user_embed, item_embed)[n, :]   (float4-vectorized)
__global__ void init_kernel(const float4* __restrict__ user,
                            const float4* __restrict__ item,
                            float4* __restrict__ out) {
    int i = blockIdx.x * blockDim.x + threadIdx.x;   // over NTOT*16 float4
    if (i >= NTOT * 16) return;
    int n = i >> 4, q = i & 15;
    float4 v = (n < N_USERS) ? user[(size_t)n * 16 + q]
                             : item[(size_t)(n - N_USERS) * 16 + q];
    // out row stride = 4*64 floats = 64 float4; hop-0 slice = first 16 float4
    out[(size_t)n * 64 + q] = v;
}

// Edge-parallel SpMM hop: one 64-lane wave per edge, lane = dim.
// Reads slice `hop` (already message-masked), scatters into slice `hop+1`.
__global__ __launch_bounds__(256) void scatter_kernel(
        const int*   __restrict__ rows,
        const int*   __restrict__ cols,
        const float* __restrict__ vals,
        const void*  __restrict__ emask,
        const int*   __restrict__ flag,
        float*       __restrict__ out,
        int hop) {
    int wid  = blockIdx.x * 4 + (threadIdx.x >> 6);   // edge index
    int lane = threadIdx.x & 63;
    if (wid >= NNZ) return;

    size_t mi = (size_t)hop * NNZ + wid;
    bool keep;
    if (*flag) keep = ((const unsigned char*)emask)[mi] != 0;
    else       keep = ((const unsigned int*)emask)[mi]  != 0;
    if (!keep) return;                                 // wave-uniform exit

    int   r = rows[wid];
    int   c = cols[wid];
    float v = vals[wid] * EDGE_SCALE;

    float x = out[(size_t)c * 256 + (size_t)hop * 64 + lane];
    atomicAdd(&out[(size_t)r * 256 + (size_t)(hop + 1) * 64 + lane], v * x);
}

// Message dropout on slice hop+1: out = mask ? out * (1/0.9) : 0
__global__ void mess_kernel(const void* __restrict__ mmask,
                            const int*  __restrict__ flag,
                            float*      __restrict__ out,
                            int hop) {
    int i = blockIdx.x * blockDim.x + threadIdx.x;    // over NTOT*D
    if (i >= NTOT * D) return;
    int n = i >> 6, d = i & 63;
    size_t mi = (size_t)hop * NTOT * D + i;
    bool keep;
    if (*flag) keep = ((const unsigned char*)mmask)[mi] != 0;
    else       keep = ((const unsigned int*)mmask)[mi]  != 0;
    size_t oi = (size_t)n * 256 + (size_t)(hop + 1) * 64 + d;
    out[oi] = keep ? out[oi] * MESS_SCALE : 0.0f;
}

extern "C" void kernel_launch(void* const* d_in, const int* in_sizes, int n_in,
                              void* d_out, int out_size, void* d_ws, size_t ws_size,
                              hipStream_t stream) {
    const float* user  = (const float*)d_in[0];
    const float* item  = (const float*)d_in[1];
    const int*   rows  = (const int*)d_in[2];
    const int*   cols  = (const int*)d_in[3];
    const float* vals  = (const float*)d_in[4];
    const void*  emask = d_in[5];
    const void*  mmask = d_in[6];
    float* out = (float*)d_out;
    int*   flag = (int*)d_ws;

    detect_mask_kernel<<<1, 256, 0, stream>>>((const unsigned int*)emask, flag);

    // d_out is re-poisoned before every timed call: zero it ourselves.
    hipMemsetAsync(d_out, 0, (size_t)out_size * sizeof(float), stream);

    init_kernel<<<(NTOT * 16 + 255) / 256, 256, 0, stream>>>(
        (const float4*)user, (const float4*)item, (float4*)out);

    for (int hop = 0; hop < NHOPS; ++hop) {
        scatter_kernel<<<(NNZ + 3) / 4, 256, 0, stream>>>(
            rows, cols, vals, emask, flag, out, hop);
        mess_kernel<<<(NTOT * D + 255) / 256, 256, 0, stream>>>(
            mmask, flag, out, hop);
    }
}

// Round 4
// 3949.754 us; speedup vs baseline: 1.4284x; 1.4284x over previous
//
#include <hip/hip_runtime.h>

#define N_USERS 100000
#define N_ITEMS 50000
#define NTOT    150000
#define NNZ     10000000
#define D       64
#define NHOPS   3
#define EDGE_SCALE 2.0f
#define MESS_SCALE (1.0f/0.9f)

// ---- workspace layout (bytes) ----
#define OFF_FLAG 0
#define OFF_CNT  256
#define OFF_RPTR (OFF_CNT  + 600064)   // NTOT*4 = 600000, padded
#define OFF_CUR  (OFF_RPTR + 600064)
#define OFF_REC  (OFF_CUR  + 600064)
#define WS_NEED  ((size_t)OFF_REC + (size_t)NNZ * 16)

// ---------------------------------------------------------------------------
// Mask-dtype self-calibration (jnp bool may land as 1-byte or 4-byte).
// Scan first 1024 u32 words of edge_mask: packed 1-byte bools produce words
// outside {0,1,0x3f800000} with overwhelming probability.
// ---------------------------------------------------------------------------
__global__ void detect_mask_kernel(const unsigned int* __restrict__ em,
                                   int* __restrict__ flag) {
    __shared__ int s;
    if (threadIdx.x == 0) s = 0;
    __syncthreads();
    for (int i = threadIdx.x; i < 1024; i += blockDim.x) {
        unsigned int w = em[i];
        if (w != 0u && w != 1u && w != 0x3f800000u) s = 1;
    }
    __syncthreads();
    if (threadIdx.x == 0) *flag = s;
}

// out[n, 0, :] = concat(user_embed, item_embed)[n, :]
__global__ void init_kernel(const float4* __restrict__ user,
                            const float4* __restrict__ item,
                            float4* __restrict__ out) {
    int i = blockIdx.x * blockDim.x + threadIdx.x;   // over NTOT*16 float4
    if (i >= NTOT * 16) return;
    int n = i >> 4, q = i & 15;
    float4 v = (n < N_USERS) ? user[(size_t)n * 16 + q]
                             : item[(size_t)(n - N_USERS) * 16 + q];
    out[(size_t)n * 64 + q] = v;   // row stride 64 float4; hop0 = first 16
}

// ---------------- CSR build ----------------
__global__ void hist_kernel(const int* __restrict__ rows, int* __restrict__ cnt) {
    int e = blockIdx.x * blockDim.x + threadIdx.x;
    if (e < NNZ) atomicAdd(&cnt[rows[e]], 1);
}

// block sums over 1024-element tiles
__global__ void scan1_kernel(const int* __restrict__ cnt, int* __restrict__ part) {
    __shared__ int s[256];
    int b = blockIdx.x, t = threadIdx.x;
    int base = b * 1024 + t * 4, sum = 0;
    #pragma unroll
    for (int k = 0; k < 4; ++k) { int i = base + k; if (i < NTOT) sum += cnt[i]; }
    s[t] = sum; __syncthreads();
    for (int off = 128; off > 0; off >>= 1) {
        if (t < off) s[t] += s[t + off];
        __syncthreads();
    }
    if (t == 0) part[b] = s[0];
}

// exclusive scan of <=256 partials, single block
__global__ void scan2_kernel(int* __restrict__ part, int npart) {
    __shared__ int s[256];
    int t = threadIdx.x;
    int my = (t < npart) ? part[t] : 0;
    s[t] = my; __syncthreads();
    for (int off = 1; off < 256; off <<= 1) {
        int v = (t >= off) ? s[t - off] : 0;
        __syncthreads();
        s[t] += v;
        __syncthreads();
    }
    if (t < npart) part[t] = s[t] - my;   // exclusive
}

// per-tile exclusive scan + partial offset -> row_ptr, cursor
__global__ void scan3_kernel(const int* __restrict__ cnt, const int* __restrict__ part,
                             int* __restrict__ rptr, int* __restrict__ cur) {
    __shared__ int s[256];
    int b = blockIdx.x, t = threadIdx.x;
    int base = b * 1024 + t * 4;
    int v[4], sum = 0;
    #pragma unroll
    for (int k = 0; k < 4; ++k) { int i = base + k; v[k] = (i < NTOT) ? cnt[i] : 0; sum += v[k]; }
    int my = sum;
    s[t] = sum; __syncthreads();
    for (int off = 1; off < 256; off <<= 1) {
        int x = (t >= off) ? s[t - off] : 0;
        __syncthreads();
        s[t] += x;
        __syncthreads();
    }
    int run = s[t] - my + part[b];
    #pragma unroll
    for (int k = 0; k < 4; ++k) {
        int i = base + k;
        if (i < NTOT) { rptr[i] = run; cur[i] = run; }
        run += v[k];
    }
    if (b == 0 && t == 0) rptr[NTOT] = NNZ;
}

// scatter edges into CSR order; pre-apply all 3 hops' edge masks to vals
__global__ void build_kernel(const int* __restrict__ rows, const int* __restrict__ cols,
                             const float* __restrict__ vals,
                             const void* __restrict__ emask, const int* __restrict__ flag,
                             int* __restrict__ cur, float4* __restrict__ rec) {
    int e = blockIdx.x * blockDim.x + threadIdx.x;
    if (e >= NNZ) return;
    int pos = atomicAdd(&cur[rows[e]], 1);
    float v = vals[e] * EDGE_SCALE;
    float m0, m1, m2;
    if (*flag) {
        const unsigned char* em = (const unsigned char*)emask;
        m0 = em[e] ? v : 0.0f;
        m1 = em[(size_t)NNZ + e] ? v : 0.0f;
        m2 = em[(size_t)2 * NNZ + e] ? v : 0.0f;
    } else {
        const unsigned int* em = (const unsigned int*)emask;
        m0 = em[e] ? v : 0.0f;
        m1 = em[(size_t)NNZ + e] ? v : 0.0f;
        m2 = em[(size_t)2 * NNZ + e] ? v : 0.0f;
    }
    rec[pos] = make_float4(__int_as_float(cols[e]), m0, m1, m2);
}

// ---------------- hops: one 64-lane wave per row, lane = dim ----------------
template <int HOP>
__global__ __launch_bounds__(256) void hop_kernel(
        const float4* __restrict__ rec,
        const int*    __restrict__ rptr,
        const void*   __restrict__ mmask,
        const int*    __restrict__ flag,
        float*        __restrict__ out) {
    int r    = blockIdx.x * 4 + (threadIdx.x >> 6);
    int lane = threadIdx.x & 63;
    if (r >= NTOT) return;
    int beg = rptr[r], end = rptr[r + 1];
    float acc = 0.0f;
    for (int i = beg; i < end; ++i) {
        float4 e = rec[i];                                    // broadcast (same addr)
        float mv = (HOP == 0) ? e.y : (HOP == 1) ? e.z : e.w;
        if (mv != 0.0f) {                                     // wave-uniform skip
            int c = __float_as_int(e.x);
            acc += mv * out[(size_t)c * 256 + HOP * 64 + lane];
        }
    }
    // fused message dropout + store (every output element written exactly once)
    size_t mi = (size_t)HOP * NTOT * D + (size_t)r * D + lane;
    bool keep;
    if (*flag) keep = ((const unsigned char*)mmask)[mi] != 0;
    else       keep = ((const unsigned int*)mmask)[mi]  != 0;
    out[(size_t)r * 256 + (HOP + 1) * 64 + lane] = keep ? acc * MESS_SCALE : 0.0f;
}

// ---------------- fallback (if ws too small): round-1 atomic path ----------------
__global__ __launch_bounds__(256) void scatter_fb_kernel(
        const int* __restrict__ rows, const int* __restrict__ cols,
        const float* __restrict__ vals, const void* __restrict__ emask,
        const int* __restrict__ flag, float* __restrict__ out, int hop) {
    int wid  = blockIdx.x * 4 + (threadIdx.x >> 6);
    int lane = threadIdx.x & 63;
    if (wid >= NNZ) return;
    size_t mi = (size_t)hop * NNZ + wid;
    bool keep;
    if (*flag) keep = ((const unsigned char*)emask)[mi] != 0;
    else       keep = ((const unsigned int*)emask)[mi]  != 0;
    if (!keep) return;
    float v = vals[wid] * EDGE_SCALE;
    float x = out[(size_t)cols[wid] * 256 + (size_t)hop * 64 + lane];
    atomicAdd(&out[(size_t)rows[wid] * 256 + (size_t)(hop + 1) * 64 + lane], v * x);
}

__global__ void mess_fb_kernel(const void* __restrict__ mmask, const int* __restrict__ flag,
                               float* __restrict__ out, int hop) {
    int i = blockIdx.x * blockDim.x + threadIdx.x;
    if (i >= NTOT * D) return;
    int n = i >> 6, d = i & 63;
    size_t mi = (size_t)hop * NTOT * D + i;
    bool keep;
    if (*flag) keep = ((const unsigned char*)mmask)[mi] != 0;
    else       keep = ((const unsigned int*)mmask)[mi]  != 0;
    size_t oi = (size_t)n * 256 + (size_t)(hop + 1) * 64 + d;
    out[oi] = keep ? out[oi] * MESS_SCALE : 0.0f;
}

extern "C" void kernel_launch(void* const* d_in, const int* in_sizes, int n_in,
                              void* d_out, int out_size, void* d_ws, size_t ws_size,
                              hipStream_t stream) {
    const float* user  = (const float*)d_in[0];
    const float* item  = (const float*)d_in[1];
    const int*   rows  = (const int*)d_in[2];
    const int*   cols  = (const int*)d_in[3];
    const float* vals  = (const float*)d_in[4];
    const void*  emask = d_in[5];
    const void*  mmask = d_in[6];
    float* out = (float*)d_out;

    char* ws = (char*)d_ws;
    int*    flag = (int*)(ws + OFF_FLAG);
    int*    cnt  = (int*)(ws + OFF_CNT);
    int*    rptr = (int*)(ws + OFF_RPTR);
    int*    cur  = (int*)(ws + OFF_CUR);
    float4* rec  = (float4*)(ws + OFF_REC);
    // scan partials live at the head of the rec region: scan1/2/3 finish
    // reading them before build_kernel first writes rec. No aliasing hazard.
    int*    part = (int*)(ws + OFF_REC);

    detect_mask_kernel<<<1, 256, 0, stream>>>((const unsigned int*)emask, flag);

    if (ws_size >= WS_NEED) {
        // ---- CSR gather path ----
        hipMemsetAsync(cnt, 0, (size_t)NTOT * sizeof(int), stream);
        hist_kernel<<<(NNZ + 255) / 256, 256, 0, stream>>>(rows, cnt);
        const int NB = (NTOT + 1023) / 1024;     // 147 partials
        scan1_kernel<<<NB, 256, 0, stream>>>(cnt, part);
        scan2_kernel<<<1, 256, 0, stream>>>(part, NB);
        scan3_kernel<<<NB, 256, 0, stream>>>(cnt, part, rptr, cur);
        build_kernel<<<(NNZ + 255) / 256, 256, 0, stream>>>(
            rows, cols, vals, emask, flag, cur, rec);
        init_kernel<<<(NTOT * 16 + 255) / 256, 256, 0, stream>>>(
            (const float4*)user, (const float4*)item, (float4*)out);
        const int HB = (NTOT + 3) / 4;            // 4 rows (waves) per block
        hop_kernel<0><<<HB, 256, 0, stream>>>(rec, rptr, mmask, flag, out);
        hop_kernel<1><<<HB, 256, 0, stream>>>(rec, rptr, mmask, flag, out);
        hop_kernel<2><<<HB, 256, 0, stream>>>(rec, rptr, mmask, flag, out);
    } else {
        // ---- fallback: atomic scatter path ----
        hipMemsetAsync(d_out, 0, (size_t)out_size * sizeof(float), stream);
        init_kernel<<<(NTOT * 16 + 255) / 256, 256, 0, stream>>>(
            (const float4*)user, (const float4*)item, (float4*)out);
        for (int hop = 0; hop < NHOPS; ++hop) {
            scatter_fb_kernel<<<(NNZ + 3) / 4, 256, 0, stream>>>(
                rows, cols, vals, emask, flag, out, hop);
            mess_fb_kernel<<<(NTOT * D + 255) / 256, 256, 0, stream>>>(
                mmask, flag, out, hop);
        }
    }
}

// Round 5
// 1881.161 us; speedup vs baseline: 2.9991x; 2.0996x over previous
//
#include <hip/hip_runtime.h>

#define N_USERS 100000
#define N_ITEMS 50000
#define NTOT    150000
#define NNZ     10000000
#define D       64
#define NHOPS   3
#define EDGE_SCALE 2.0f
#define MESS_SCALE (1.0f/0.9f)

// padded record capacity: every row padded up to multiple of 8
#define NREC_MAX (NNZ + 7 * NTOT)     // 11,050,000

// ---- workspace layout (bytes) ----
#define OFF_FLAG 0
#define OFF_CNT  256
#define OFF_RPTR (OFF_CNT  + 600064)   // NTOT*4 = 600000, padded
#define OFF_CUR  (OFF_RPTR + 600064)
#define OFF_REC  (OFF_CUR  + 600064)
#define WS_NEED  ((size_t)OFF_REC + (size_t)NREC_MAX * 8)

// ---------------------------------------------------------------------------
// Mask-dtype self-calibration (jnp bool may land as 1-byte or 4-byte).
// ---------------------------------------------------------------------------
__global__ void detect_mask_kernel(const unsigned int* __restrict__ em,
                                   int* __restrict__ flag) {
    __shared__ int s;
    if (threadIdx.x == 0) s = 0;
    __syncthreads();
    for (int i = threadIdx.x; i < 1024; i += blockDim.x) {
        unsigned int w = em[i];
        if (w != 0u && w != 1u && w != 0x3f800000u) s = 1;
    }
    __syncthreads();
    if (threadIdx.x == 0) *flag = s;
}

// out[n, 0, :] = concat(user_embed, item_embed)[n, :]
__global__ void init_kernel(const float4* __restrict__ user,
                            const float4* __restrict__ item,
                            float4* __restrict__ out) {
    int i = blockIdx.x * blockDim.x + threadIdx.x;   // over NTOT*16 float4
    if (i >= NTOT * 16) return;
    int n = i >> 4, q = i & 15;
    float4 v = (n < N_USERS) ? user[(size_t)n * 16 + q]
                             : item[(size_t)(n - N_USERS) * 16 + q];
    out[(size_t)n * 64 + q] = v;   // row stride 64 float4; hop0 = first 16
}

// ---------------- CSR build ----------------
__global__ void hist_kernel(const int* __restrict__ rows, int* __restrict__ cnt) {
    int e = blockIdx.x * blockDim.x + threadIdx.x;
    if (e < NNZ) atomicAdd(&cnt[rows[e]], 1);
}

#define PAD8(c) (((c) + 7) & ~7)

// block sums of PADDED counts over 1024-element tiles
__global__ void scan1_kernel(const int* __restrict__ cnt, int* __restrict__ part) {
    __shared__ int s[256];
    int b = blockIdx.x, t = threadIdx.x;
    int base = b * 1024 + t * 4, sum = 0;
    #pragma unroll
    for (int k = 0; k < 4; ++k) { int i = base + k; if (i < NTOT) sum += PAD8(cnt[i]); }
    s[t] = sum; __syncthreads();
    for (int off = 128; off > 0; off >>= 1) {
        if (t < off) s[t] += s[t + off];
        __syncthreads();
    }
    if (t == 0) part[b] = s[0];
}

// exclusive scan of <=256 partials, single block
__global__ void scan2_kernel(int* __restrict__ part, int npart) {
    __shared__ int s[256];
    int t = threadIdx.x;
    int my = (t < npart) ? part[t] : 0;
    s[t] = my; __syncthreads();
    for (int off = 1; off < 256; off <<= 1) {
        int v = (t >= off) ? s[t - off] : 0;
        __syncthreads();
        s[t] += v;
        __syncthreads();
    }
    if (t < npart) part[t] = s[t] - my;   // exclusive
}

// per-tile exclusive scan of PADDED counts + partial offset -> row_ptr, cursor
__global__ void scan3_kernel(const int* __restrict__ cnt, const int* __restrict__ part,
                             int* __restrict__ rptr, int* __restrict__ cur) {
    __shared__ int s[256];
    int b = blockIdx.x, t = threadIdx.x;
    int base = b * 1024 + t * 4;
    int v[4], sum = 0;
    #pragma unroll
    for (int k = 0; k < 4; ++k) {
        int i = base + k;
        v[k] = (i < NTOT) ? PAD8(cnt[i]) : 0;
        sum += v[k];
    }
    int my = sum;
    s[t] = sum; __syncthreads();
    for (int off = 1; off < 256; off <<= 1) {
        int x = (t >= off) ? s[t - off] : 0;
        __syncthreads();
        s[t] += x;
        __syncthreads();
    }
    int run = s[t] - my + part[b];
    #pragma unroll
    for (int k = 0; k < 4; ++k) {
        int i = base + k;
        if (i < NTOT) { rptr[i] = run; cur[i] = run; }
        run += v[k];
    }
    if (b == 0 && t == 0) {
        // total padded count goes in rptr[NTOT]: last partial-scan block fixes it
    }
}

// set rptr[NTOT] = total padded records (sum of all padded counts)
__global__ void fixtot_kernel(const int* __restrict__ cnt, int* __restrict__ rptr) {
    // single block reduction over cnt via padded values, 256 threads
    __shared__ int s[256];
    int t = threadIdx.x, sum = 0;
    for (int i = t; i < NTOT; i += 256) sum += PAD8(cnt[i]);
    s[t] = sum; __syncthreads();
    for (int off = 128; off > 0; off >>= 1) {
        if (t < off) s[t] += s[t + off];
        __syncthreads();
    }
    if (t == 0) rptr[NTOT] = s[0];
}

// fill pad slots [rptr[r]+cnt[r], rptr[r+1]) with zero records
__global__ void pad_kernel(const int* __restrict__ rptr, const int* __restrict__ cnt,
                           uint2* __restrict__ rec) {
    int r = blockIdx.x * blockDim.x + threadIdx.x;
    if (r >= NTOT) return;
    int b = rptr[r] + cnt[r], e = rptr[r + 1];
    for (int j = b; j < e; ++j) rec[j] = make_uint2(0u, 0u);
}

// scatter edges into CSR order; pack col(18b) + 3 mask bits (24/25/26) + val*2
__global__ void build_kernel(const int* __restrict__ rows, const int* __restrict__ cols,
                             const float* __restrict__ vals,
                             const void* __restrict__ emask, const int* __restrict__ flag,
                             int* __restrict__ cur, uint2* __restrict__ rec) {
    int e = blockIdx.x * blockDim.x + threadIdx.x;
    if (e >= NNZ) return;
    int pos = atomicAdd(&cur[rows[e]], 1);
    float v = vals[e] * EDGE_SCALE;
    unsigned int cw = (unsigned int)cols[e];
    if (*flag) {
        const unsigned char* em = (const unsigned char*)emask;
        cw |= (em[e] ? 1u : 0u) << 24;
        cw |= (em[(size_t)NNZ + e] ? 1u : 0u) << 25;
        cw |= (em[(size_t)2 * NNZ + e] ? 1u : 0u) << 26;
    } else {
        const unsigned int* em = (const unsigned int*)emask;
        cw |= (em[e] ? 1u : 0u) << 24;
        cw |= (em[(size_t)NNZ + e] ? 1u : 0u) << 25;
        cw |= (em[(size_t)2 * NNZ + e] ? 1u : 0u) << 26;
    }
    rec[pos] = make_uint2(cw, __float_as_uint(v));
}

// ---------------- hops: one 64-lane wave per row, lane = dim ----------------
// Branchless, 8-wide unrolled, tail-free (rows padded to multiples of 8).
// Dropped edges gather row 0 (L1-hot) with v=0 -> contribute nothing.
template <int HOP>
__global__ __launch_bounds__(256) void hop_kernel(
        const uint2* __restrict__ rec,
        const int*   __restrict__ rptr,
        const void*  __restrict__ mmask,
        const int*   __restrict__ flag,
        float*       __restrict__ out) {
    int r    = blockIdx.x * 4 + (threadIdx.x >> 6);
    int lane = threadIdx.x & 63;
    if (r >= NTOT) return;
    int beg = __builtin_amdgcn_readfirstlane(rptr[r]);
    int end = __builtin_amdgcn_readfirstlane(rptr[r + 1]);

    const float* __restrict__ src = out + HOP * 64 + lane;  // + row*256 per edge
    float a0 = 0.0f, a1 = 0.0f, a2 = 0.0f, a3 = 0.0f;

    for (int i = beg; i < end; i += 8) {
        #pragma unroll
        for (int k = 0; k < 8; ++k) {
            uint2 e = rec[i + k];                     // wave-uniform (scalar-load)
            unsigned int keep = (e.x >> (24 + HOP)) & 1u;
            unsigned int roff = keep ? (e.x & 0x3FFFFu) * 256u : 0u;
            float v = keep ? __uint_as_float(e.y) : 0.0f;
            float x = src[roff];
            if (k % 4 == 0) a0 += v * x;
            else if (k % 4 == 1) a1 += v * x;
            else if (k % 4 == 2) a2 += v * x;
            else a3 += v * x;
        }
    }
    float acc = (a0 + a1) + (a2 + a3);

    // fused message dropout + store (every output element written exactly once)
    size_t mi = (size_t)HOP * NTOT * D + (size_t)r * D + lane;
    bool keep;
    if (*flag) keep = ((const unsigned char*)mmask)[mi] != 0;
    else       keep = ((const unsigned int*)mmask)[mi]  != 0;
    out[(size_t)r * 256 + (HOP + 1) * 64 + lane] = keep ? acc * MESS_SCALE : 0.0f;
}

// ---------------- fallback (if ws too small): atomic scatter path ----------------
__global__ __launch_bounds__(256) void scatter_fb_kernel(
        const int* __restrict__ rows, const int* __restrict__ cols,
        const float* __restrict__ vals, const void* __restrict__ emask,
        const int* __restrict__ flag, float* __restrict__ out, int hop) {
    int wid  = blockIdx.x * 4 + (threadIdx.x >> 6);
    int lane = threadIdx.x & 63;
    if (wid >= NNZ) return;
    size_t mi = (size_t)hop * NNZ + wid;
    bool keep;
    if (*flag) keep = ((const unsigned char*)emask)[mi] != 0;
    else       keep = ((const unsigned int*)emask)[mi]  != 0;
    if (!keep) return;
    float v = vals[wid] * EDGE_SCALE;
    float x = out[(size_t)cols[wid] * 256 + (size_t)hop * 64 + lane];
    atomicAdd(&out[(size_t)rows[wid] * 256 + (size_t)(hop + 1) * 64 + lane], v * x);
}

__global__ void mess_fb_kernel(const void* __restrict__ mmask, const int* __restrict__ flag,
                               float* __restrict__ out, int hop) {
    int i = blockIdx.x * blockDim.x + threadIdx.x;
    if (i >= NTOT * D) return;
    int n = i >> 6, d = i & 63;
    size_t mi = (size_t)hop * NTOT * D + i;
    bool keep;
    if (*flag) keep = ((const unsigned char*)mmask)[mi] != 0;
    else       keep = ((const unsigned int*)mmask)[mi]  != 0;
    size_t oi = (size_t)n * 256 + (size_t)(hop + 1) * 64 + d;
    out[oi] = keep ? out[oi] * MESS_SCALE : 0.0f;
}

extern "C" void kernel_launch(void* const* d_in, const int* in_sizes, int n_in,
                              void* d_out, int out_size, void* d_ws, size_t ws_size,
                              hipStream_t stream) {
    const float* user  = (const float*)d_in[0];
    const float* item  = (const float*)d_in[1];
    const int*   rows  = (const int*)d_in[2];
    const int*   cols  = (const int*)d_in[3];
    const float* vals  = (const float*)d_in[4];
    const void*  emask = d_in[5];
    const void*  mmask = d_in[6];
    float* out = (float*)d_out;

    char* ws = (char*)d_ws;
    int*   flag = (int*)(ws + OFF_FLAG);
    int*   cnt  = (int*)(ws + OFF_CNT);
    int*   rptr = (int*)(ws + OFF_RPTR);
    int*   cur  = (int*)(ws + OFF_CUR);
    uint2* rec  = (uint2*)(ws + OFF_REC);
    // scan partials live at the head of the rec region: all scan reads finish
    // before build/pad first write rec (stream-ordered). No aliasing hazard.
    int*   part = (int*)(ws + OFF_REC);

    detect_mask_kernel<<<1, 256, 0, stream>>>((const unsigned int*)emask, flag);

    if (ws_size >= WS_NEED) {
        // ---- CSR gather path ----
        hipMemsetAsync(cnt, 0, (size_t)NTOT * sizeof(int), stream);
        hist_kernel<<<(NNZ + 255) / 256, 256, 0, stream>>>(rows, cnt);
        const int NB = (NTOT + 1023) / 1024;     // 147 partials
        scan1_kernel<<<NB, 256, 0, stream>>>(cnt, part);
        scan2_kernel<<<1, 256, 0, stream>>>(part, NB);
        scan3_kernel<<<NB, 256, 0, stream>>>(cnt, part, rptr, cur);
        fixtot_kernel<<<1, 256, 0, stream>>>(cnt, rptr);
        pad_kernel<<<(NTOT + 255) / 256, 256, 0, stream>>>(rptr, cnt, rec);
        build_kernel<<<(NNZ + 255) / 256, 256, 0, stream>>>(
            rows, cols, vals, emask, flag, cur, rec);
        init_kernel<<<(NTOT * 16 + 255) / 256, 256, 0, stream>>>(
            (const float4*)user, (const float4*)item, (float4*)out);
        const int HB = (NTOT + 3) / 4;            // 4 rows (waves) per block
        hop_kernel<0><<<HB, 256, 0, stream>>>(rec, rptr, mmask, flag, out);
        hop_kernel<1><<<HB, 256, 0, stream>>>(rec, rptr, mmask, flag, out);
        hop_kernel<2><<<HB, 256, 0, stream>>>(rec, rptr, mmask, flag, out);
    } else {
        // ---- fallback: atomic scatter path ----
        hipMemsetAsync(d_out, 0, (size_t)out_size * sizeof(float), stream);
        init_kernel<<<(NTOT * 16 + 255) / 256, 256, 0, stream>>>(
            (const float4*)user, (const float4*)item, (float4*)out);
        for (int hop = 0; hop < NHOPS; ++hop) {
            scatter_fb_kernel<<<(NNZ + 3) / 4, 256, 0, stream>>>(
                rows, cols, vals, emask, flag, out, hop);
            mess_fb_kernel<<<(NTOT * D + 255) / 256, 256, 0, stream>>>(
                mmask, flag, out, hop);
        }
    }
}

// Round 7
// 1819.528 us; speedup vs baseline: 3.1007x; 1.0339x over previous
//
#include <hip/hip_runtime.h>

#define N_USERS 100000
#define N_ITEMS 50000
#define NTOT    150000
#define NNZ     10000000
#define D       64
#define NHOPS   3
#define EDGE_SCALE 2.0f
#define MESS_SCALE (1.0f/0.9f)

// padded record capacity: every row padded up to multiple of 8
#define NREC_MAX (NNZ + 7 * NTOT)     // 11,050,000
// row buckets for binned build: 256 rows per bucket
#define NBKT ((NTOT + 255) / 256)     // 586
#define EPB  4096                     // edges per block in pass A (16/thread)
#define NBLKA ((NNZ + EPB - 1) / EPB) // 2442

// ---- workspace layout (bytes) ----
#define OFF_FLAG 0
#define OFF_CNT  256
#define OFF_RPTR (OFF_CNT  + 600064)   // NTOT*4 = 600000, padded
#define OFF_CUR  (OFF_RPTR + 600064)
#define OFF_BST  (OFF_CUR  + 600064)   // (NBKT+1)*4, padded to 4096
#define OFF_BCUR (OFF_BST  + 4096)
#define OFF_REC  (OFF_BCUR + 4096)
#define OFF_STG  (OFF_REC  + (size_t)NREC_MAX * 8)
#define WS_BINNED ((size_t)OFF_STG + (size_t)NNZ * 8)
#define WS_OLD    ((size_t)OFF_REC + (size_t)NREC_MAX * 8)

// ---------------------------------------------------------------------------
// Mask-dtype self-calibration (jnp bool may land as 1-byte or 4-byte).
// ---------------------------------------------------------------------------
__global__ void detect_mask_kernel(const unsigned int* __restrict__ em,
                                   int* __restrict__ flag) {
    __shared__ int s;
    if (threadIdx.x == 0) s = 0;
    __syncthreads();
    for (int i = threadIdx.x; i < 1024; i += blockDim.x) {
        unsigned int w = em[i];
        if (w != 0u && w != 1u && w != 0x3f800000u) s = 1;
    }
    __syncthreads();
    if (threadIdx.x == 0) *flag = s;
}

// out[n, 0, :] = concat(user_embed, item_embed)[n, :]
__global__ void init_kernel(const float4* __restrict__ user,
                            const float4* __restrict__ item,
                            float4* __restrict__ out) {
    int i = blockIdx.x * blockDim.x + threadIdx.x;   // over NTOT*16 float4
    if (i >= NTOT * 16) return;
    int n = i >> 4, q = i & 15;
    float4 v = (n < N_USERS) ? user[(size_t)n * 16 + q]
                             : item[(size_t)(n - N_USERS) * 16 + q];
    out[(size_t)n * 64 + q] = v;   // row stride 64 float4; hop0 = first 16
}

// ---------------- CSR scan chain ----------------
__global__ void hist_kernel(const int* __restrict__ rows, int* __restrict__ cnt) {
    int e = blockIdx.x * blockDim.x + threadIdx.x;
    if (e < NNZ) atomicAdd(&cnt[rows[e]], 1);
}

#define PAD8(c) (((c) + 7) & ~7)

__global__ void scan1_kernel(const int* __restrict__ cnt, int* __restrict__ part) {
    __shared__ int s[256];
    int b = blockIdx.x, t = threadIdx.x;
    int base = b * 1024 + t * 4, sum = 0;
    #pragma unroll
    for (int k = 0; k < 4; ++k) { int i = base + k; if (i < NTOT) sum += PAD8(cnt[i]); }
    s[t] = sum; __syncthreads();
    for (int off = 128; off > 0; off >>= 1) {
        if (t < off) s[t] += s[t + off];
        __syncthreads();
    }
    if (t == 0) part[b] = s[0];
}

__global__ void scan2_kernel(int* __restrict__ part, int npart) {
    __shared__ int s[256];
    int t = threadIdx.x;
    int my = (t < npart) ? part[t] : 0;
    s[t] = my; __syncthreads();
    for (int off = 1; off < 256; off <<= 1) {
        int v = (t >= off) ? s[t - off] : 0;
        __syncthreads();
        s[t] += v;
        __syncthreads();
    }
    if (t < npart) part[t] = s[t] - my;   // exclusive
}

__global__ void scan3_kernel(const int* __restrict__ cnt, const int* __restrict__ part,
                             int* __restrict__ rptr, int* __restrict__ cur) {
    __shared__ int s[256];
    int b = blockIdx.x, t = threadIdx.x;
    int base = b * 1024 + t * 4;
    int v[4], sum = 0;
    #pragma unroll
    for (int k = 0; k < 4; ++k) {
        int i = base + k;
        v[k] = (i < NTOT) ? PAD8(cnt[i]) : 0;
        sum += v[k];
    }
    int my = sum;
    s[t] = sum; __syncthreads();
    for (int off = 1; off < 256; off <<= 1) {
        int x = (t >= off) ? s[t - off] : 0;
        __syncthreads();
        s[t] += x;
        __syncthreads();
    }
    int run = s[t] - my + part[b];
    #pragma unroll
    for (int k = 0; k < 4; ++k) {
        int i = base + k;
        if (i < NTOT) { rptr[i] = run; cur[i] = run; }
        run += v[k];
    }
}

__global__ void fixtot_kernel(const int* __restrict__ cnt, int* __restrict__ rptr) {
    __shared__ int s[256];
    int t = threadIdx.x, sum = 0;
    for (int i = t; i < NTOT; i += 256) sum += PAD8(cnt[i]);
    s[t] = sum; __syncthreads();
    for (int off = 128; off > 0; off >>= 1) {
        if (t < off) s[t] += s[t + off];
        __syncthreads();
    }
    if (t == 0) rptr[NTOT] = s[0];
}

// fill pad slots [rptr[r]+cnt[r], rptr[r+1]) with zero records
__global__ void pad_kernel(const int* __restrict__ rptr, const int* __restrict__ cnt,
                           uint2* __restrict__ rec) {
    int r = blockIdx.x * blockDim.x + threadIdx.x;
    if (r >= NTOT) return;
    int b = rptr[r] + cnt[r], e = rptr[r + 1];
    for (int j = b; j < e; ++j) rec[j] = make_uint2(0u, 0u);
}

// ---------------- binned build: pass A (bin into buckets, chunked writes) ----
// staged word: col[0:18) | masks[18:21) | (row&255)[21:29)
__global__ __launch_bounds__(256) void binA_kernel(
        const int* __restrict__ rows, const int* __restrict__ cols,
        const float* __restrict__ vals,
        const void* __restrict__ emask, const int* __restrict__ flag,
        int* __restrict__ bcur, uint2* __restrict__ staged) {
    __shared__ int h[NBKT];
    int t = threadIdx.x;
    long long base = (long long)blockIdx.x * EPB;
    for (int b = t; b < NBKT; b += 256) h[b] = 0;
    __syncthreads();
    unsigned int rw[16];
    unsigned short rnk[16];
    #pragma unroll
    for (int k = 0; k < 16; ++k) {
        long long e = base + (long long)k * 256 + t;
        rw[k] = 0xFFFFFFFFu; rnk[k] = 0;
        if (e < NNZ) {
            unsigned int r = (unsigned int)rows[e];
            rw[k] = r;
            rnk[k] = (unsigned short)atomicAdd(&h[r >> 8], 1);
        }
    }
    __syncthreads();
    for (int b = t; b < NBKT; b += 256) {
        int c = h[b];
        h[b] = c ? atomicAdd(&bcur[b], c) : 0;   // bucket base for this block
    }
    __syncthreads();
    bool bytes = (*flag != 0);
    #pragma unroll
    for (int k = 0; k < 16; ++k) {
        long long e = base + (long long)k * 256 + t;
        if (e < NNZ) {
            unsigned int r = rw[k];
            unsigned int p = (unsigned int)cols[e] & 0x3FFFFu;
            unsigned int m;
            if (bytes) {
                const unsigned char* em = (const unsigned char*)emask;
                m = (em[e] ? 1u : 0u)
                  | ((em[(size_t)NNZ + e] ? 1u : 0u) << 1)
                  | ((em[2 * (size_t)NNZ + e] ? 1u : 0u) << 2);
            } else {
                const unsigned int* em = (const unsigned int*)emask;
                m = (em[e] ? 1u : 0u)
                  | ((em[(size_t)NNZ + e] ? 1u : 0u) << 1)
                  | ((em[2 * (size_t)NNZ + e] ? 1u : 0u) << 2);
            }
            p |= m << 18;
            p |= (r & 255u) << 21;
            float v = vals[e] * EDGE_SCALE;
            int pos = h[r >> 8] + (int)rnk[k];
            staged[pos] = make_uint2(p, __float_as_uint(v));
        }
    }
}

// bucket sums (unpadded counts) -> bcur (used as bsum temp)
__global__ void bsum_kernel(const int* __restrict__ cnt, int* __restrict__ bsum) {
    __shared__ int s[256];
    int b = blockIdx.x, t = threadIdx.x;
    int i = b * 256 + t;
    s[t] = (i < NTOT) ? cnt[i] : 0;
    __syncthreads();
    for (int off = 128; off > 0; off >>= 1) {
        if (t < off) s[t] += s[t + off];
        __syncthreads();
    }
    if (t == 0) bsum[b] = s[0];
}

// exclusive scan of NBKT bucket sums (LDS, single block); bst & bcur = starts
__global__ void bscan_kernel(int* __restrict__ bst, int* __restrict__ bcur) {
    __shared__ int s[NBKT];
    int t = threadIdx.x;
    for (int b = t; b < NBKT; b += 256) s[b] = bcur[b];
    __syncthreads();
    if (t == 0) {
        int run = 0;
        for (int b = 0; b < NBKT; ++b) { int c = s[b]; s[b] = run; run += c; }
        bst[NBKT] = run;
    }
    __syncthreads();
    for (int b = t; b < NBKT; b += 256) { bst[b] = s[b]; bcur[b] = s[b]; }
}

// pass B: one block per bucket; scatter within L2-resident CSR region,
// positions from LDS cursors seeded with rptr.
__global__ __launch_bounds__(256) void binB_kernel(
        const int* __restrict__ rptr, const int* __restrict__ bst,
        const uint2* __restrict__ staged, uint2* __restrict__ rec) {
    __shared__ int lc[256];
    int b = blockIdx.x, t = threadIdx.x;
    int gr = b * 256 + t;
    lc[t] = (gr < NTOT) ? rptr[gr] : 0;
    __syncthreads();
    int s0 = bst[b], s1 = bst[b + 1];
    for (int i = s0 + t; i < s1; i += 256) {
        uint2 e = staged[i];
        int r8 = (int)((e.x >> 21) & 255u);
        int pos = atomicAdd(&lc[r8], 1);
        unsigned int cw = (e.x & 0x3FFFFu) | (((e.x >> 18) & 7u) << 24);
        rec[pos] = make_uint2(cw, e.y);
    }
}

// ---------------- old direct build (mid-tier fallback) ----------------
__global__ void build_kernel(const int* __restrict__ rows, const int* __restrict__ cols,
                             const float* __restrict__ vals,
                             const void* __restrict__ emask, const int* __restrict__ flag,
                             int* __restrict__ cur, uint2* __restrict__ rec) {
    int e = blockIdx.x * blockDim.x + threadIdx.x;
    if (e >= NNZ) return;
    int pos = atomicAdd(&cur[rows[e]], 1);
    float v = vals[e] * EDGE_SCALE;
    unsigned int cw = (unsigned int)cols[e];
    if (*flag) {
        const unsigned char* em = (const unsigned char*)emask;
        cw |= (em[e] ? 1u : 0u) << 24;
        cw |= (em[(size_t)NNZ + e] ? 1u : 0u) << 25;
        cw |= (em[(size_t)2 * NNZ + e] ? 1u : 0u) << 26;
    } else {
        const unsigned int* em = (const unsigned int*)emask;
        cw |= (em[e] ? 1u : 0u) << 24;
        cw |= (em[(size_t)NNZ + e] ? 1u : 0u) << 25;
        cw |= (em[(size_t)2 * NNZ + e] ? 1u : 0u) << 26;
    }
    rec[pos] = make_uint2(cw, __float_as_uint(v));
}

// ---------------- hops: one 64-lane wave per row, lane = dim ----------------
// Branchless, 8-wide unrolled, tail-free (rows padded to multiples of 8).
// rec stream read non-temporally (read-once) to keep gather lines in L3.
template <int HOP>
__global__ __launch_bounds__(256) void hop_kernel(
        const uint2* __restrict__ rec,
        const int*   __restrict__ rptr,
        const void*  __restrict__ mmask,
        const int*   __restrict__ flag,
        float*       __restrict__ out) {
    int r    = blockIdx.x * 4 + (threadIdx.x >> 6);
    int lane = threadIdx.x & 63;
    if (r >= NTOT) return;
    int beg = __builtin_amdgcn_readfirstlane(rptr[r]);
    int end = __builtin_amdgcn_readfirstlane(rptr[r + 1]);

    const unsigned long long* __restrict__ rp = (const unsigned long long*)rec;
    const float* __restrict__ src = out + HOP * 64 + lane;  // + col*256 per edge
    float a0 = 0.0f, a1 = 0.0f, a2 = 0.0f, a3 = 0.0f;

    for (int i = beg; i < end; i += 8) {
        #pragma unroll
        for (int k = 0; k < 8; ++k) {
            unsigned long long rr = __builtin_nontemporal_load(&rp[i + k]);
            unsigned int ex = (unsigned int)rr;
            unsigned int keep = (ex >> (24 + HOP)) & 1u;
            unsigned int roff = keep ? (ex & 0x3FFFFu) * 256u : 0u;
            float v = keep ? __uint_as_float((unsigned int)(rr >> 32)) : 0.0f;
            float x = src[roff];
            if (k % 4 == 0) a0 += v * x;
            else if (k % 4 == 1) a1 += v * x;
            else if (k % 4 == 2) a2 += v * x;
            else a3 += v * x;
        }
    }
    float acc = (a0 + a1) + (a2 + a3);

    // fused message dropout + store (every output element written exactly once)
    size_t mi = (size_t)HOP * NTOT * D + (size_t)r * D + lane;
    bool keep;
    if (*flag) keep = ((const unsigned char*)mmask)[mi] != 0;
    else       keep = ((const unsigned int*)mmask)[mi]  != 0;
    out[(size_t)r * 256 + (HOP + 1) * 64 + lane] = keep ? acc * MESS_SCALE : 0.0f;
}

// ---------------- fallback (tiny ws): atomic scatter path ----------------
__global__ __launch_bounds__(256) void scatter_fb_kernel(
        const int* __restrict__ rows, const int* __restrict__ cols,
        const float* __restrict__ vals, const void* __restrict__ emask,
        const int* __restrict__ flag, float* __restrict__ out, int hop) {
    int wid  = blockIdx.x * 4 + (threadIdx.x >> 6);
    int lane = threadIdx.x & 63;
    if (wid >= NNZ) return;
    size_t mi = (size_t)hop * NNZ + wid;
    bool keep;
    if (*flag) keep = ((const unsigned char*)emask)[mi] != 0;
    else       keep = ((const unsigned int*)emask)[mi]  != 0;
    if (!keep) return;
    float v = vals[wid] * EDGE_SCALE;
    float x = out[(size_t)cols[wid] * 256 + (size_t)hop * 64 + lane];
    atomicAdd(&out[(size_t)rows[wid] * 256 + (size_t)(hop + 1) * 64 + lane], v * x);
}

__global__ void mess_fb_kernel(const void* __restrict__ mmask, const int* __restrict__ flag,
                               float* __restrict__ out, int hop) {
    int i = blockIdx.x * blockDim.x + threadIdx.x;
    if (i >= NTOT * D) return;
    int n = i >> 6, d = i & 63;
    size_t mi = (size_t)hop * NTOT * D + i;
    bool keep;
    if (*flag) keep = ((const unsigned char*)mmask)[mi] != 0;
    else       keep = ((const unsigned int*)mmask)[mi]  != 0;
    size_t oi = (size_t)n * 256 + (size_t)(hop + 1) * 64 + d;
    out[oi] = keep ? out[oi] * MESS_SCALE : 0.0f;
}

extern "C" void kernel_launch(void* const* d_in, const int* in_sizes, int n_in,
                              void* d_out, int out_size, void* d_ws, size_t ws_size,
                              hipStream_t stream) {
    const float* user  = (const float*)d_in[0];
    const float* item  = (const float*)d_in[1];
    const int*   rows  = (const int*)d_in[2];
    const int*   cols  = (const int*)d_in[3];
    const float* vals  = (const float*)d_in[4];
    const void*  emask = d_in[5];
    const void*  mmask = d_in[6];
    float* out = (float*)d_out;

    char* ws = (char*)d_ws;
    int*   flag = (int*)(ws + OFF_FLAG);
    int*   cnt  = (int*)(ws + OFF_CNT);
    int*   rptr = (int*)(ws + OFF_RPTR);
    int*   cur  = (int*)(ws + OFF_CUR);
    int*   bst  = (int*)(ws + OFF_BST);
    int*   bcur = (int*)(ws + OFF_BCUR);
    uint2* rec  = (uint2*)(ws + OFF_REC);
    uint2* stg  = (uint2*)(ws + OFF_STG);
    // scan partials live at the head of the rec region: all scan reads finish
    // before pad/build first write rec (stream-ordered). No aliasing hazard.
    int*   part = (int*)(ws + OFF_REC);

    detect_mask_kernel<<<1, 256, 0, stream>>>((const unsigned int*)emask, flag);

    if (ws_size >= WS_OLD) {
        // ---- shared CSR scan chain ----
        hipMemsetAsync(cnt, 0, (size_t)NTOT * sizeof(int), stream);
        hist_kernel<<<(NNZ + 255) / 256, 256, 0, stream>>>(rows, cnt);
        const int NB = (NTOT + 1023) / 1024;     // 147 partials
        scan1_kernel<<<NB, 256, 0, stream>>>(cnt, part);
        scan2_kernel<<<1, 256, 0, stream>>>(part, NB);
        scan3_kernel<<<NB, 256, 0, stream>>>(cnt, part, rptr, cur);
        fixtot_kernel<<<1, 256, 0, stream>>>(cnt, rptr);
        pad_kernel<<<(NTOT + 255) / 256, 256, 0, stream>>>(rptr, cnt, rec);

        if (ws_size >= WS_BINNED) {
            // ---- binned build: chunked appends, then L2-local scatter ----
            bsum_kernel<<<NBKT, 256, 0, stream>>>(cnt, bcur);
            bscan_kernel<<<1, 256, 0, stream>>>(bst, bcur);
            binA_kernel<<<NBLKA, 256, 0, stream>>>(
                rows, cols, vals, emask, flag, bcur, stg);
            binB_kernel<<<NBKT, 256, 0, stream>>>(rptr, bst, stg, rec);
        } else {
            build_kernel<<<(NNZ + 255) / 256, 256, 0, stream>>>(
                rows, cols, vals, emask, flag, cur, rec);
        }

        init_kernel<<<(NTOT * 16 + 255) / 256, 256, 0, stream>>>(
            (const float4*)user, (const float4*)item, (float4*)out);
        const int HB = (NTOT + 3) / 4;            // 4 rows (waves) per block
        hop_kernel<0><<<HB, 256, 0, stream>>>(rec, rptr, mmask, flag, out);
        hop_kernel<1><<<HB, 256, 0, stream>>>(rec, rptr, mmask, flag, out);
        hop_kernel<2><<<HB, 256, 0, stream>>>(rec, rptr, mmask, flag, out);
    } else {
        // ---- fallback: atomic scatter path ----
        hipMemsetAsync(d_out, 0, (size_t)out_size * sizeof(float), stream);
        init_kernel<<<(NTOT * 16 + 255) / 256, 256, 0, stream>>>(
            (const float4*)user, (const float4*)item, (float4*)out);
        for (int hop = 0; hop < NHOPS; ++hop) {
            scatter_fb_kernel<<<(NNZ + 3) / 4, 256, 0, stream>>>(
                rows, cols, vals, emask, flag, out, hop);
            mess_fb_kernel<<<(NTOT * D + 255) / 256, 256, 0, stream>>>(
                mmask, flag, out, hop);
        }
    }
}

// Round 10
// 1490.277 us; speedup vs baseline: 3.7857x; 1.2209x over previous
//
#include <hip/hip_runtime.h>

#define N_USERS 100000
#define N_ITEMS 50000
#define NTOT    150000
#define NNZ     10000000
#define D       64
#define NHOPS   3
#define EDGE_SCALE 2.0f
#define MESS_SCALE (1.0f/0.9f)

// padded record capacity: every row padded up to multiple of 8
#define NREC_MAX (NNZ + 7 * NTOT)     // 11,050,000
// row buckets for binned build: 256 rows per bucket
#define NBKT ((NTOT + 255) / 256)     // 586
#define EPB  4096                     // edges per block in pass A (16/thread)
#define NBLKA ((NNZ + EPB - 1) / EPB) // 2442
#define NBLK_BC 592                   // blocks for bucket-count kernel

// ---- workspace layout (bytes) ----
#define OFF_FLAG 0
#define OFF_CNT  256
#define OFF_RPTR (OFF_CNT  + 600064)   // NTOT*4 = 600000, padded
#define OFF_CUR  (OFF_RPTR + 600064)
#define OFF_BST  (OFF_CUR  + 600064)   // (NBKT+1)*4, padded to 4096
#define OFF_BCUR (OFF_BST  + 4096)
#define OFF_REC  (OFF_BCUR + 4096)
#define OFF_STG  (OFF_REC  + (size_t)NREC_MAX * 8)
#define WS_BINNED ((size_t)OFF_STG + (size_t)NNZ * 8)
#define WS_OLD    ((size_t)OFF_REC + (size_t)NREC_MAX * 8)

// ---------------------------------------------------------------------------
// Mask-dtype self-calibration (jnp bool may land as 1-byte or 4-byte).
// ---------------------------------------------------------------------------
__global__ void detect_mask_kernel(const unsigned int* __restrict__ em,
                                   int* __restrict__ flag) {
    __shared__ int s;
    if (threadIdx.x == 0) s = 0;
    __syncthreads();
    for (int i = threadIdx.x; i < 1024; i += blockDim.x) {
        unsigned int w = em[i];
        if (w != 0u && w != 1u && w != 0x3f800000u) s = 1;
    }
    __syncthreads();
    if (threadIdx.x == 0) *flag = s;
}

// out[n, 0, :] = concat(user_embed, item_embed)[n, :]
__global__ void init_kernel(const float4* __restrict__ user,
                            const float4* __restrict__ item,
                            float4* __restrict__ out) {
    int i = blockIdx.x * blockDim.x + threadIdx.x;   // over NTOT*16 float4
    if (i >= NTOT * 16) return;
    int n = i >> 4, q = i & 15;
    float4 v = (n < N_USERS) ? user[(size_t)n * 16 + q]
                             : item[(size_t)(n - N_USERS) * 16 + q];
    out[(size_t)n * 64 + q] = v;   // row stride 64 float4; hop0 = first 16
}

// ---------------- bucket counting (replaces contended global hist) ----------
// LDS-private 586-counter histogram; flush = 586 atomics/block (347K total,
// vs 10M write-through atomics of the old hist_kernel).
__global__ __launch_bounds__(256) void bktcnt_kernel(const int* __restrict__ rows,
                                                     int* __restrict__ bsum) {
    __shared__ int h[NBKT];
    int t = threadIdx.x;
    for (int b = t; b < NBKT; b += 256) h[b] = 0;
    __syncthreads();
    for (long long e = (long long)blockIdx.x * 256 + t; e < NNZ;
         e += (long long)NBLK_BC * 256)
        atomicAdd(&h[((unsigned int)rows[e]) >> 8], 1);
    __syncthreads();
    for (int b = t; b < NBKT; b += 256) {
        int c = h[b];
        if (c) atomicAdd(&bsum[b], c);
    }
}

// exclusive scan of NBKT bucket sums (in bcur) -> bst & bcur = bucket starts
__global__ void bscan_kernel(int* __restrict__ bst, int* __restrict__ bcur) {
    __shared__ int s[NBKT];
    int t = threadIdx.x;
    for (int b = t; b < NBKT; b += 256) s[b] = bcur[b];
    __syncthreads();
    if (t == 0) {
        int run = 0;
        for (int b = 0; b < NBKT; ++b) { int c = s[b]; s[b] = run; run += c; }
        bst[NBKT] = run;
    }
    __syncthreads();
    for (int b = t; b < NBKT; b += 256) { bst[b] = s[b]; bcur[b] = s[b]; }
}

// ---------------- binned build: pass A (bin into buckets, chunked writes) ----
// staged word: col[0:18) | masks[18:21) | (row&255)[21:29)
__global__ __launch_bounds__(256) void binA_kernel(
        const int* __restrict__ rows, const int* __restrict__ cols,
        const float* __restrict__ vals,
        const void* __restrict__ emask, const int* __restrict__ flag,
        int* __restrict__ bcur, uint2* __restrict__ staged) {
    __shared__ int h[NBKT];
    int t = threadIdx.x;
    long long base = (long long)blockIdx.x * EPB;
    for (int b = t; b < NBKT; b += 256) h[b] = 0;
    __syncthreads();
    unsigned int rw[16];
    unsigned short rnk[16];
    #pragma unroll
    for (int k = 0; k < 16; ++k) {
        long long e = base + (long long)k * 256 + t;
        rw[k] = 0xFFFFFFFFu; rnk[k] = 0;
        if (e < NNZ) {
            unsigned int r = (unsigned int)rows[e];
            rw[k] = r;
            rnk[k] = (unsigned short)atomicAdd(&h[r >> 8], 1);
        }
    }
    __syncthreads();
    for (int b = t; b < NBKT; b += 256) {
        int c = h[b];
        h[b] = c ? atomicAdd(&bcur[b], c) : 0;   // bucket base for this block
    }
    __syncthreads();
    bool bytes = (*flag != 0);
    #pragma unroll
    for (int k = 0; k < 16; ++k) {
        long long e = base + (long long)k * 256 + t;
        if (e < NNZ) {
            unsigned int r = rw[k];
            unsigned int p = (unsigned int)cols[e] & 0x3FFFFu;
            unsigned int m;
            if (bytes) {
                const unsigned char* em = (const unsigned char*)emask;
                m = (em[e] ? 1u : 0u)
                  | ((em[(size_t)NNZ + e] ? 1u : 0u) << 1)
                  | ((em[2 * (size_t)NNZ + e] ? 1u : 0u) << 2);
            } else {
                const unsigned int* em = (const unsigned int*)emask;
                m = (em[e] ? 1u : 0u)
                  | ((em[(size_t)NNZ + e] ? 1u : 0u) << 1)
                  | ((em[2 * (size_t)NNZ + e] ? 1u : 0u) << 2);
            }
            p |= m << 18;
            p |= (r & 255u) << 21;
            float v = vals[e] * EDGE_SCALE;
            int pos = h[r >> 8] + (int)rnk[k];
            staged[pos] = make_uint2(p, __float_as_uint(v));
        }
    }
}

// per-row counts from bucket-grouped staged records: LDS hist, plain stores
__global__ __launch_bounds__(256) void bcnt_kernel(const int* __restrict__ bst,
                                                   const uint2* __restrict__ staged,
                                                   int* __restrict__ cnt) {
    __shared__ int h[256];
    int b = blockIdx.x, t = threadIdx.x;
    h[t] = 0;
    __syncthreads();
    int s0 = bst[b], s1 = bst[b + 1];
    for (int i = s0 + t; i < s1; i += 256)
        atomicAdd(&h[(staged[i].x >> 21) & 255u], 1);
    __syncthreads();
    int gr = b * 256 + t;
    if (gr < NTOT) cnt[gr] = h[t];
}

// ---------------- CSR scan chain (from cnt) ----------------
// (hist_kernel retained only for the mid-tier fallback path)
__global__ void hist_kernel(const int* __restrict__ rows, int* __restrict__ cnt) {
    int e = blockIdx.x * blockDim.x + threadIdx.x;
    if (e < NNZ) atomicAdd(&cnt[rows[e]], 1);
}

#define PAD8(c) (((c) + 7) & ~7)

__global__ void scan1_kernel(const int* __restrict__ cnt, int* __restrict__ part) {
    __shared__ int s[256];
    int b = blockIdx.x, t = threadIdx.x;
    int base = b * 1024 + t * 4, sum = 0;
    #pragma unroll
    for (int k = 0; k < 4; ++k) { int i = base + k; if (i < NTOT) sum += PAD8(cnt[i]); }
    s[t] = sum; __syncthreads();
    for (int off = 128; off > 0; off >>= 1) {
        if (t < off) s[t] += s[t + off];
        __syncthreads();
    }
    if (t == 0) part[b] = s[0];
}

__global__ void scan2_kernel(int* __restrict__ part, int npart) {
    __shared__ int s[256];
    int t = threadIdx.x;
    int my = (t < npart) ? part[t] : 0;
    s[t] = my; __syncthreads();
    for (int off = 1; off < 256; off <<= 1) {
        int v = (t >= off) ? s[t - off] : 0;
        __syncthreads();
        s[t] += v;
        __syncthreads();
    }
    if (t < npart) part[t] = s[t] - my;   // exclusive
}

__global__ void scan3_kernel(const int* __restrict__ cnt, const int* __restrict__ part,
                             int* __restrict__ rptr, int* __restrict__ cur) {
    __shared__ int s[256];
    int b = blockIdx.x, t = threadIdx.x;
    int base = b * 1024 + t * 4;
    int v[4], sum = 0;
    #pragma unroll
    for (int k = 0; k < 4; ++k) {
        int i = base + k;
        v[k] = (i < NTOT) ? PAD8(cnt[i]) : 0;
        sum += v[k];
    }
    int my = sum;
    s[t] = sum; __syncthreads();
    for (int off = 1; off < 256; off <<= 1) {
        int x = (t >= off) ? s[t - off] : 0;
        __syncthreads();
        s[t] += x;
        __syncthreads();
    }
    int run = s[t] - my + part[b];
    #pragma unroll
    for (int k = 0; k < 4; ++k) {
        int i = base + k;
        if (i < NTOT) { rptr[i] = run; cur[i] = run; }
        run += v[k];
    }
}

__global__ void fixtot_kernel(const int* __restrict__ cnt, int* __restrict__ rptr) {
    __shared__ int s[256];
    int t = threadIdx.x, sum = 0;
    for (int i = t; i < NTOT; i += 256) sum += PAD8(cnt[i]);
    s[t] = sum; __syncthreads();
    for (int off = 128; off > 0; off >>= 1) {
        if (t < off) s[t] += s[t + off];
        __syncthreads();
    }
    if (t == 0) rptr[NTOT] = s[0];
}

// fill pad slots [rptr[r]+cnt[r], rptr[r+1]) with zero records
__global__ void pad_kernel(const int* __restrict__ rptr, const int* __restrict__ cnt,
                           uint2* __restrict__ rec) {
    int r = blockIdx.x * blockDim.x + threadIdx.x;
    if (r >= NTOT) return;
    int b = rptr[r] + cnt[r], e = rptr[r + 1];
    for (int j = b; j < e; ++j) rec[j] = make_uint2(0u, 0u);
}

// pass B: one block per bucket; scatter within L2-resident CSR region,
// positions from LDS cursors seeded with rptr.
__global__ __launch_bounds__(256) void binB_kernel(
        const int* __restrict__ rptr, const int* __restrict__ bst,
        const uint2* __restrict__ staged, uint2* __restrict__ rec) {
    __shared__ int lc[256];
    int b = blockIdx.x, t = threadIdx.x;
    int gr = b * 256 + t;
    lc[t] = (gr < NTOT) ? rptr[gr] : 0;
    __syncthreads();
    int s0 = bst[b], s1 = bst[b + 1];
    for (int i = s0 + t; i < s1; i += 256) {
        uint2 e = staged[i];
        int r8 = (int)((e.x >> 21) & 255u);
        int pos = atomicAdd(&lc[r8], 1);
        unsigned int cw = (e.x & 0x3FFFFu) | (((e.x >> 18) & 7u) << 24);
        rec[pos] = make_uint2(cw, e.y);
    }
}

// ---------------- old direct build (mid-tier fallback) ----------------
__global__ void build_kernel(const int* __restrict__ rows, const int* __restrict__ cols,
                             const float* __restrict__ vals,
                             const void* __restrict__ emask, const int* __restrict__ flag,
                             int* __restrict__ cur, uint2* __restrict__ rec) {
    int e = blockIdx.x * blockDim.x + threadIdx.x;
    if (e >= NNZ) return;
    int pos = atomicAdd(&cur[rows[e]], 1);
    float v = vals[e] * EDGE_SCALE;
    unsigned int cw = (unsigned int)cols[e];
    if (*flag) {
        const unsigned char* em = (const unsigned char*)emask;
        cw |= (em[e] ? 1u : 0u) << 24;
        cw |= (em[(size_t)NNZ + e] ? 1u : 0u) << 25;
        cw |= (em[(size_t)2 * NNZ + e] ? 1u : 0u) << 26;
    } else {
        const unsigned int* em = (const unsigned int*)emask;
        cw |= (em[e] ? 1u : 0u) << 24;
        cw |= (em[(size_t)NNZ + e] ? 1u : 0u) << 25;
        cw |= (em[(size_t)2 * NNZ + e] ? 1u : 0u) << 26;
    }
    rec[pos] = make_uint2(cw, __float_as_uint(v));
}

// ---------------- hops: one 64-lane wave per row, lane = dim ----------------
// Branchless, 8-wide unrolled, tail-free (rows padded to multiples of 8).
// rec stream read non-temporally (read-once) to keep gather lines in L3.
template <int HOP>
__global__ __launch_bounds__(256) void hop_kernel(
        const uint2* __restrict__ rec,
        const int*   __restrict__ rptr,
        const void*  __restrict__ mmask,
        const int*   __restrict__ flag,
        float*       __restrict__ out) {
    int r    = blockIdx.x * 4 + (threadIdx.x >> 6);
    int lane = threadIdx.x & 63;
    if (r >= NTOT) return;
    int beg = __builtin_amdgcn_readfirstlane(rptr[r]);
    int end = __builtin_amdgcn_readfirstlane(rptr[r + 1]);

    const unsigned long long* __restrict__ rp = (const unsigned long long*)rec;
    const float* __restrict__ src = out + HOP * 64 + lane;  // + col*256 per edge
    float a0 = 0.0f, a1 = 0.0f, a2 = 0.0f, a3 = 0.0f;

    for (int i = beg; i < end; i += 8) {
        #pragma unroll
        for (int k = 0; k < 8; ++k) {
            unsigned long long rr = __builtin_nontemporal_load(&rp[i + k]);
            unsigned int ex = (unsigned int)rr;
            unsigned int keep = (ex >> (24 + HOP)) & 1u;
            unsigned int roff = keep ? (ex & 0x3FFFFu) * 256u : 0u;
            float v = keep ? __uint_as_float((unsigned int)(rr >> 32)) : 0.0f;
            float x = src[roff];
            if (k % 4 == 0) a0 += v * x;
            else if (k % 4 == 1) a1 += v * x;
            else if (k % 4 == 2) a2 += v * x;
            else a3 += v * x;
        }
    }
    float acc = (a0 + a1) + (a2 + a3);

    // fused message dropout + store (every output element written exactly once)
    size_t mi = (size_t)HOP * NTOT * D + (size_t)r * D + lane;
    bool keep;
    if (*flag) keep = ((const unsigned char*)mmask)[mi] != 0;
    else       keep = ((const unsigned int*)mmask)[mi]  != 0;
    out[(size_t)r * 256 + (HOP + 1) * 64 + lane] = keep ? acc * MESS_SCALE : 0.0f;
}

// ---------------- fallback (tiny ws): atomic scatter path ----------------
__global__ __launch_bounds__(256) void scatter_fb_kernel(
        const int* __restrict__ rows, const int* __restrict__ cols,
        const float* __restrict__ vals, const void* __restrict__ emask,
        const int* __restrict__ flag, float* __restrict__ out, int hop) {
    int wid  = blockIdx.x * 4 + (threadIdx.x >> 6);
    int lane = threadIdx.x & 63;
    if (wid >= NNZ) return;
    size_t mi = (size_t)hop * NNZ + wid;
    bool keep;
    if (*flag) keep = ((const unsigned char*)emask)[mi] != 0;
    else       keep = ((const unsigned int*)emask)[mi]  != 0;
    if (!keep) return;
    float v = vals[wid] * EDGE_SCALE;
    float x = out[(size_t)cols[wid] * 256 + (size_t)hop * 64 + lane];
    atomicAdd(&out[(size_t)rows[wid] * 256 + (size_t)(hop + 1) * 64 + lane], v * x);
}

__global__ void mess_fb_kernel(const void* __restrict__ mmask, const int* __restrict__ flag,
                               float* __restrict__ out, int hop) {
    int i = blockIdx.x * blockDim.x + threadIdx.x;
    if (i >= NTOT * D) return;
    int n = i >> 6, d = i & 63;
    size_t mi = (size_t)hop * NTOT * D + i;
    bool keep;
    if (*flag) keep = ((const unsigned char*)mmask)[mi] != 0;
    else       keep = ((const unsigned int*)mmask)[mi]  != 0;
    size_t oi = (size_t)n * 256 + (size_t)(hop + 1) * 64 + d;
    out[oi] = keep ? out[oi] * MESS_SCALE : 0.0f;
}

extern "C" void kernel_launch(void* const* d_in, const int* in_sizes, int n_in,
                              void* d_out, int out_size, void* d_ws, size_t ws_size,
                              hipStream_t stream) {
    const float* user  = (const float*)d_in[0];
    const float* item  = (const float*)d_in[1];
    const int*   rows  = (const int*)d_in[2];
    const int*   cols  = (const int*)d_in[3];
    const float* vals  = (const float*)d_in[4];
    const void*  emask = d_in[5];
    const void*  mmask = d_in[6];
    float* out = (float*)d_out;

    char* ws = (char*)d_ws;
    int*   flag = (int*)(ws + OFF_FLAG);
    int*   cnt  = (int*)(ws + OFF_CNT);
    int*   rptr = (int*)(ws + OFF_RPTR);
    int*   cur  = (int*)(ws + OFF_CUR);
    int*   bst  = (int*)(ws + OFF_BST);
    int*   bcur = (int*)(ws + OFF_BCUR);
    uint2* rec  = (uint2*)(ws + OFF_REC);
    uint2* stg  = (uint2*)(ws + OFF_STG);
    // scan partials live at the head of the rec region: all scan reads finish
    // before pad/binB first write rec (stream-ordered). No aliasing hazard.
    int*   part = (int*)(ws + OFF_REC);

    detect_mask_kernel<<<1, 256, 0, stream>>>((const unsigned int*)emask, flag);

    const int NB = (NTOT + 1023) / 1024;     // 147 partials

    if (ws_size >= WS_BINNED) {
        // ---- binned path: no contended global histogram anywhere ----
        hipMemsetAsync(bcur, 0, 4096, stream);
        bktcnt_kernel<<<NBLK_BC, 256, 0, stream>>>(rows, bcur);       // bucket sums
        bscan_kernel<<<1, 256, 0, stream>>>(bst, bcur);               // bucket starts
        binA_kernel<<<NBLKA, 256, 0, stream>>>(
            rows, cols, vals, emask, flag, bcur, stg);                // bin edges
        bcnt_kernel<<<NBKT, 256, 0, stream>>>(bst, stg, cnt);         // per-row counts
        scan1_kernel<<<NB, 256, 0, stream>>>(cnt, part);
        scan2_kernel<<<1, 256, 0, stream>>>(part, NB);
        scan3_kernel<<<NB, 256, 0, stream>>>(cnt, part, rptr, cur);
        fixtot_kernel<<<1, 256, 0, stream>>>(cnt, rptr);
        pad_kernel<<<(NTOT + 255) / 256, 256, 0, stream>>>(rptr, cnt, rec);
        binB_kernel<<<NBKT, 256, 0, stream>>>(rptr, bst, stg, rec);   // CSR scatter
        init_kernel<<<(NTOT * 16 + 255) / 256, 256, 0, stream>>>(
            (const float4*)user, (const float4*)item, (float4*)out);
        const int HB = (NTOT + 3) / 4;            // 4 rows (waves) per block
        hop_kernel<0><<<HB, 256, 0, stream>>>(rec, rptr, mmask, flag, out);
        hop_kernel<1><<<HB, 256, 0, stream>>>(rec, rptr, mmask, flag, out);
        hop_kernel<2><<<HB, 256, 0, stream>>>(rec, rptr, mmask, flag, out);
    } else if (ws_size >= WS_OLD) {
        // ---- mid-tier: global hist + direct build ----
        hipMemsetAsync(cnt, 0, (size_t)NTOT * sizeof(int), stream);
        hist_kernel<<<(NNZ + 255) / 256, 256, 0, stream>>>(rows, cnt);
        scan1_kernel<<<NB, 256, 0, stream>>>(cnt, part);
        scan2_kernel<<<1, 256, 0, stream>>>(part, NB);
        scan3_kernel<<<NB, 256, 0, stream>>>(cnt, part, rptr, cur);
        fixtot_kernel<<<1, 256, 0, stream>>>(cnt, rptr);
        pad_kernel<<<(NTOT + 255) / 256, 256, 0, stream>>>(rptr, cnt, rec);
        build_kernel<<<(NNZ + 255) / 256, 256, 0, stream>>>(
            rows, cols, vals, emask, flag, cur, rec);
        init_kernel<<<(NTOT * 16 + 255) / 256, 256, 0, stream>>>(
            (const float4*)user, (const float4*)item, (float4*)out);
        const int HB = (NTOT + 3) / 4;
        hop_kernel<0><<<HB, 256, 0, stream>>>(rec, rptr, mmask, flag, out);
        hop_kernel<1><<<HB, 256, 0, stream>>>(rec, rptr, mmask, flag, out);
        hop_kernel<2><<<HB, 256, 0, stream>>>(rec, rptr, mmask, flag, out);
    } else {
        // ---- fallback: atomic scatter path ----
        hipMemsetAsync(d_out, 0, (size_t)out_size * sizeof(float), stream);
        init_kernel<<<(NTOT * 16 + 255) / 256, 256, 0, stream>>>(
            (const float4*)user, (const float4*)item, (float4*)out);
        for (int hop = 0; hop < NHOPS; ++hop) {
            scatter_fb_kernel<<<(NNZ + 3) / 4, 256, 0, stream>>>(
                rows, cols, vals, emask, flag, out, hop);
            mess_fb_kernel<<<(NTOT * D + 255) / 256, 256, 0, stream>>>(
                mmask, flag, out, hop);
        }
    }
}